// Round 2
// baseline (3071.491 us; speedup 1.0000x reference)
//
#include <hip/hip_runtime.h>

#define N_NODES   50000
#define N_EDGES   800000
#define IN_FEAT   128
#define N_CLASSES 64

// ---------------------------------------------------------------------------
// deg[i] = 1 (self loop); then atomically count in-edges; then dinv = rsqrt.
// ---------------------------------------------------------------------------
__global__ void init_deg_kernel(float* deg, int n) {
    int i = blockIdx.x * blockDim.x + threadIdx.x;
    if (i < n) deg[i] = 1.0f;  // self-loop contributes 1 to every node's degree
}

__global__ void count_deg_kernel(const int* __restrict__ col, float* deg, int e) {
    int i = blockIdx.x * blockDim.x + threadIdx.x;
    if (i < e) atomicAdd(&deg[col[i]], 1.0f);
}

__global__ void dinv_kernel(float* deg, int n) {
    int i = blockIdx.x * blockDim.x + threadIdx.x;
    if (i < n) deg[i] = rsqrtf(deg[i]);  // deg >= 1 always, no zero guard needed
}

// ---------------------------------------------------------------------------
// One propagation hop: xout[c] += dinv[r]*dinv[c]*xin[r] over edges + self loops.
// 32 lanes per edge; each lane handles 4 consecutive features (float4 gather,
// 4 scalar fp32 atomics).
// ---------------------------------------------------------------------------
__global__ void hop_kernel(const int* __restrict__ row,
                           const int* __restrict__ col,
                           const float* __restrict__ dinv,
                           const float* __restrict__ xin,
                           float* __restrict__ xout,
                           int e, int n) {
    long long tid = (long long)blockIdx.x * blockDim.x + threadIdx.x;
    int edge = (int)(tid >> 5);
    int lane = (int)(tid & 31);
    int total = e + n;
    if (edge >= total) return;

    int r, c;
    if (edge < e) {
        r = row[edge];
        c = col[edge];
    } else {
        r = c = edge - e;  // self loop
    }
    float w = dinv[r] * dinv[c];

    const float4 v = *reinterpret_cast<const float4*>(xin + (size_t)r * IN_FEAT + lane * 4);
    float* dst = xout + (size_t)c * IN_FEAT + lane * 4;
    atomicAdd(dst + 0, w * v.x);
    atomicAdd(dst + 1, w * v.y);
    atomicAdd(dst + 2, w * v.z);
    atomicAdd(dst + 3, w * v.w);
}

// ---------------------------------------------------------------------------
// out[n,c] = sum_f h[n,f] * W[c,f] + b[c].  One 64-thread block per node;
// h-row staged in LDS (broadcast reads, conflict-free).
// ---------------------------------------------------------------------------
__global__ __launch_bounds__(64) void out_gemm_kernel(const float* __restrict__ h,
                                                      const float* __restrict__ W,
                                                      const float* __restrict__ b,
                                                      float* __restrict__ out,
                                                      int n) {
    __shared__ float hrow[IN_FEAT];
    int node = blockIdx.x;
    int c = threadIdx.x;
    if (node >= n) return;

    hrow[c]      = h[(size_t)node * IN_FEAT + c];
    hrow[c + 64] = h[(size_t)node * IN_FEAT + c + 64];
    __syncthreads();

    float acc = b[c];
    const float* w = W + (size_t)c * IN_FEAT;
#pragma unroll
    for (int f = 0; f < IN_FEAT; ++f) acc += hrow[f] * w[f];

    out[(size_t)node * N_CLASSES + c] = acc;
}

// ---------------------------------------------------------------------------
extern "C" void kernel_launch(void* const* d_in, const int* in_sizes, int n_in,
                              void* d_out, int out_size, void* d_ws, size_t ws_size,
                              hipStream_t stream) {
    const float* x     = (const float*)d_in[0];
    const int*   edges = (const int*)d_in[1];   // int64 in reference -> int32 on device, [2, E] flat
    const float* W     = (const float*)d_in[2]; // [64, 128]
    const float* b     = (const float*)d_in[3]; // [64]
    float*       out   = (float*)d_out;         // [N, 64]

    const int* row = edges;            // source nodes
    const int* col = edges + N_EDGES;  // target nodes

    // Workspace layout: dinv | h1 | h2
    char* ws = (char*)d_ws;
    float* dinv = (float*)ws;                                  // N floats
    float* h1   = (float*)(ws + 256 * 1024);                   // N*128 floats
    float* h2   = (float*)(ws + 256 * 1024 + (size_t)N_NODES * IN_FEAT * 4);

    const size_t hbytes = (size_t)N_NODES * IN_FEAT * sizeof(float);

    // 1) degree + dinv
    init_deg_kernel<<<(N_NODES + 255) / 256, 256, 0, stream>>>(dinv, N_NODES);
    count_deg_kernel<<<(N_EDGES + 255) / 256, 256, 0, stream>>>(col, dinv, N_EDGES);
    dinv_kernel<<<(N_NODES + 255) / 256, 256, 0, stream>>>(dinv, N_NODES);

    // 2) hop 1: x -> h1
    hipMemsetAsync(h1, 0, hbytes, stream);
    {
        long long threads = (long long)(N_EDGES + N_NODES) * 32;
        int blocks = (int)((threads + 255) / 256);
        hop_kernel<<<blocks, 256, 0, stream>>>(row, col, dinv, x, h1, N_EDGES, N_NODES);
    }

    // 3) hop 2: h1 -> h2
    hipMemsetAsync(h2, 0, hbytes, stream);
    {
        long long threads = (long long)(N_EDGES + N_NODES) * 32;
        int blocks = (int)((threads + 255) / 256);
        hop_kernel<<<blocks, 256, 0, stream>>>(row, col, dinv, h1, h2, N_EDGES, N_NODES);
    }

    // 4) linear head
    out_gemm_kernel<<<N_NODES, 64, 0, stream>>>(h2, W, b, out, N_NODES);
}

// Round 3
// 455.754 us; speedup vs baseline: 6.7394x; 6.7394x over previous
//
#include <hip/hip_runtime.h>

#define N_NODES   50000
#define N_EDGES   800000
#define IN_FEAT   128
#define N_CLASSES 64

// ---------------------------------------------------------------------------
// CSR build: histogram of targets (col), exclusive scan, fill adjacency.
// ---------------------------------------------------------------------------
__global__ void count_kernel(const int* __restrict__ col, int* __restrict__ cnt, int e) {
    int i = blockIdx.x * blockDim.x + threadIdx.x;
    if (i < e) atomicAdd(&cnt[col[i]], 1);
}

// Single-block chunked Hillis-Steele scan. 50k elements, ~50 chunks — microseconds.
__global__ __launch_bounds__(1024) void scan_kernel(const int* __restrict__ cnt,
                                                    int* __restrict__ rowptr,
                                                    int* __restrict__ cursor,
                                                    float* __restrict__ dinv,
                                                    int n) {
    __shared__ int buf[1024];
    __shared__ int carry_s;
    int t = threadIdx.x;
    if (t == 0) carry_s = 0;
    __syncthreads();
    for (int base = 0; base < n; base += 1024) {
        int i = base + t;
        int v = (i < n) ? cnt[i] : 0;
        buf[t] = v;
        __syncthreads();
        for (int off = 1; off < 1024; off <<= 1) {
            int add = (t >= off) ? buf[t - off] : 0;
            __syncthreads();
            buf[t] += add;
            __syncthreads();
        }
        int carry = carry_s;
        if (i < n) {
            int excl = carry + buf[t] - v;
            rowptr[i] = excl;
            cursor[i] = excl;
            dinv[i]   = rsqrtf((float)(v + 1));  // +1 self loop; deg>=1 always
        }
        __syncthreads();
        if (t == 1023) carry_s = carry + buf[1023];
        __syncthreads();
    }
    if (t == 0) rowptr[n] = carry_s;
}

__global__ void fill_kernel(const int* __restrict__ row, const int* __restrict__ col,
                            int* __restrict__ cursor, int* __restrict__ adj, int e) {
    int i = blockIdx.x * blockDim.x + threadIdx.x;
    if (i < e) {
        int c = col[i];
        int pos = atomicAdd(&cursor[c], 1);
        adj[pos] = row[i];
    }
}

// ---------------------------------------------------------------------------
// y = x @ W^T  (bias deferred to after propagation).  4 nodes per 256-block,
// one wave per node, lane = output class; x row staged in LDS.
// ---------------------------------------------------------------------------
__global__ __launch_bounds__(256) void gemm_kernel(const float* __restrict__ x,
                                                   const float* __restrict__ W,
                                                   float* __restrict__ y, int n) {
    __shared__ float xs[4][IN_FEAT];
    int sub  = threadIdx.x >> 6;   // wave id within block = node sub-index
    int lane = threadIdx.x & 63;   // class index
    int node = blockIdx.x * 4 + sub;
    if (node < n) {
        xs[sub][lane]      = x[(size_t)node * IN_FEAT + lane];
        xs[sub][lane + 64] = x[(size_t)node * IN_FEAT + lane + 64];
    }
    __syncthreads();
    if (node >= n) return;

    float acc = 0.0f;
    const float* w = W + (size_t)lane * IN_FEAT;
#pragma unroll
    for (int f = 0; f < IN_FEAT; ++f) acc += xs[sub][f] * w[f];
    y[(size_t)node * N_CLASSES + lane] = acc;
}

// ---------------------------------------------------------------------------
// One gather hop on 64-feature data: yout[c] = dinv[c]*( dinv[c]*yin[c]
//   + sum_{r in N_in(c)} dinv[r]*yin[r] )  [+ bias on the final hop]
// One wave per node, lane = feature.  Coalesced 256B gathers, one write.
// ---------------------------------------------------------------------------
__global__ __launch_bounds__(256) void hop_gather_kernel(const int* __restrict__ rowptr,
                                                         const int* __restrict__ adj,
                                                         const float* __restrict__ dinv,
                                                         const float* __restrict__ yin,
                                                         float* __restrict__ yout,
                                                         const float* __restrict__ bias,
                                                         int n) {
    int sub  = threadIdx.x >> 6;
    int lane = threadIdx.x & 63;
    int node = blockIdx.x * 4 + sub;
    if (node >= n) return;

    float dc = dinv[node];
    int s  = rowptr[node];
    int e2 = rowptr[node + 1];

    float acc = dc * yin[(size_t)node * N_CLASSES + lane];  // self loop (×dc again below)
    int k = s;
    for (; k + 1 < e2; k += 2) {
        int r0 = adj[k], r1 = adj[k + 1];
        float d0 = dinv[r0], d1 = dinv[r1];
        float v0 = yin[(size_t)r0 * N_CLASSES + lane];
        float v1 = yin[(size_t)r1 * N_CLASSES + lane];
        acc += d0 * v0 + d1 * v1;
    }
    if (k < e2) {
        int r = adj[k];
        acc += dinv[r] * yin[(size_t)r * N_CLASSES + lane];
    }
    acc *= dc;
    if (bias) acc += bias[lane];
    yout[(size_t)node * N_CLASSES + lane] = acc;
}

// ---------------------------------------------------------------------------
extern "C" void kernel_launch(void* const* d_in, const int* in_sizes, int n_in,
                              void* d_out, int out_size, void* d_ws, size_t ws_size,
                              hipStream_t stream) {
    const float* x     = (const float*)d_in[0];
    const int*   edges = (const int*)d_in[1];   // int64 ref -> int32 device, [2, E] flat
    const float* W     = (const float*)d_in[2]; // [64, 128]
    const float* b     = (const float*)d_in[3]; // [64]
    float*       out   = (float*)d_out;         // [N, 64]

    const int* row = edges;            // sources
    const int* col = edges + N_EDGES;  // targets

    char* ws = (char*)d_ws;
    int*   cnt    = (int*)(ws + 0);
    int*   rowptr = (int*)(ws + 256 * 1024);
    int*   cursor = (int*)(ws + 512 * 1024);
    float* dinv   = (float*)(ws + 768 * 1024);
    int*   adj    = (int*)(ws + 1024 * 1024);          // 3.2 MB
    float* y      = (float*)(ws + 8 * 1024 * 1024);    // 12.8 MB
    float* z1     = (float*)(ws + 24 * 1024 * 1024);   // 12.8 MB

    // CSR build
    hipMemsetAsync(cnt, 0, N_NODES * sizeof(int), stream);
    count_kernel<<<(N_EDGES + 255) / 256, 256, 0, stream>>>(col, cnt, N_EDGES);
    scan_kernel<<<1, 1024, 0, stream>>>(cnt, rowptr, cursor, dinv, N_NODES);
    fill_kernel<<<(N_EDGES + 255) / 256, 256, 0, stream>>>(row, col, cursor, adj, N_EDGES);

    // y = x @ W^T   (S^2 x) W^T == S^2 (x W^T)
    gemm_kernel<<<(N_NODES + 3) / 4, 256, 0, stream>>>(x, W, y, N_NODES);

    // Two propagation hops; bias fused into the last one.
    hop_gather_kernel<<<(N_NODES + 3) / 4, 256, 0, stream>>>(rowptr, adj, dinv, y, z1, nullptr, N_NODES);
    hop_gather_kernel<<<(N_NODES + 3) / 4, 256, 0, stream>>>(rowptr, adj, dinv, z1, out, b, N_NODES);
}

// Round 4
// 195.631 us; speedup vs baseline: 15.7004x; 2.3297x over previous
//
#include <hip/hip_runtime.h>

#define N_NODES   50000
#define N_EDGES   800000
#define IN_FEAT   128
#define N_CLASSES 64
#define LDS_PAD   132   // 128 + 4 floats: row-to-row bank stride = 4, float4-aligned

// ---------------------------------------------------------------------------
// CSR build: histogram of targets (col), two-level scan, fill adjacency.
// ---------------------------------------------------------------------------
__global__ void count_kernel(const int* __restrict__ col, int* __restrict__ cnt, int e) {
    int i = blockIdx.x * blockDim.x + threadIdx.x;
    if (i < e) atomicAdd(&cnt[col[i]], 1);
}

__global__ __launch_bounds__(256) void block_sum_kernel(const int* __restrict__ cnt,
                                                        int* __restrict__ bsum, int n) {
    __shared__ int s[256];
    int t = threadIdx.x;
    int i = blockIdx.x * 256 + t;
    s[t] = (i < n) ? cnt[i] : 0;
    __syncthreads();
    for (int off = 128; off > 0; off >>= 1) {
        if (t < off) s[t] += s[t + off];
        __syncthreads();
    }
    if (t == 0) bsum[blockIdx.x] = s[0];
}

__global__ __launch_bounds__(256) void scan_bsum_kernel(int* __restrict__ bsum, int nb) {
    __shared__ int s[256];
    int t = threadIdx.x;
    s[t] = (t < nb) ? bsum[t] : 0;
    __syncthreads();
    for (int off = 1; off < 256; off <<= 1) {
        int add = (t >= off) ? s[t - off] : 0;
        __syncthreads();
        s[t] += add;
        __syncthreads();
    }
    if (t < nb) bsum[t] = s[t];  // inclusive sums
}

__global__ __launch_bounds__(256) void apply_scan_kernel(const int* __restrict__ cnt,
                                                         const int* __restrict__ bsum,
                                                         int* __restrict__ rowptr,
                                                         int* __restrict__ cursor,
                                                         float* __restrict__ dinv, int n) {
    __shared__ int s[256];
    int b = blockIdx.x, t = threadIdx.x;
    int i = b * 256 + t;
    int v = (i < n) ? cnt[i] : 0;
    s[t] = v;
    __syncthreads();
    for (int off = 1; off < 256; off <<= 1) {
        int add = (t >= off) ? s[t - off] : 0;
        __syncthreads();
        s[t] += add;
        __syncthreads();
    }
    int boff = (b > 0) ? bsum[b - 1] : 0;
    if (i < n) {
        int excl = boff + s[t] - v;
        rowptr[i] = excl;
        cursor[i] = excl;
        dinv[i]   = rsqrtf((float)(v + 1));  // +1 self loop
    }
    if (i == n - 1) rowptr[n] = boff + s[t];
}

__global__ void fill_kernel(const int* __restrict__ row, const int* __restrict__ col,
                            int* __restrict__ cursor, int* __restrict__ adj, int e) {
    int i = blockIdx.x * blockDim.x + threadIdx.x;
    if (i < e) {
        int c = col[i];
        int pos = atomicAdd(&cursor[c], 1);
        adj[pos] = row[i];
    }
}

// ---------------------------------------------------------------------------
// Tiled y = x @ W^T.  64 rows x 64 cols per 256-thread block; x-tile and W in
// LDS (pad 132 -> bank stride 4); each thread owns a 4x4 register tile at
// rows {rg+16i}, cols {cg+16j}  (strided mapping => conflict-free b128 reads).
// ---------------------------------------------------------------------------
__global__ __launch_bounds__(256) void gemm_kernel(const float* __restrict__ x,
                                                   const float* __restrict__ W,
                                                   float* __restrict__ y, int n) {
    __shared__ float xs[64][LDS_PAD];
    __shared__ float ws[64][LDS_PAD];
    int t = threadIdx.x;
    int rowbase = blockIdx.x * 64;

    for (int i = t; i < 64 * 32; i += 256) {
        int r  = i >> 5;
        int kk = i & 31;
        *(float4*)(&ws[r][kk * 4]) = *(const float4*)(W + (size_t)r * IN_FEAT + kk * 4);
        int gr = rowbase + r;
        float4 v = make_float4(0.f, 0.f, 0.f, 0.f);
        if (gr < n) v = *(const float4*)(x + (size_t)gr * IN_FEAT + kk * 4);
        *(float4*)(&xs[r][kk * 4]) = v;
    }
    __syncthreads();

    int rg = t >> 4;   // 0..15 -> rows rg, rg+16, rg+32, rg+48
    int cg = t & 15;   // 0..15 -> cols cg, cg+16, cg+32, cg+48
    float acc[4][4] = {};

    for (int kk = 0; kk < 32; ++kk) {
        float4 a[4], bb[4];
#pragma unroll
        for (int i = 0; i < 4; ++i) a[i]  = *(float4*)(&xs[rg + 16 * i][kk * 4]);
#pragma unroll
        for (int j = 0; j < 4; ++j) bb[j] = *(float4*)(&ws[cg + 16 * j][kk * 4]);
#pragma unroll
        for (int i = 0; i < 4; ++i)
#pragma unroll
            for (int j = 0; j < 4; ++j)
                acc[i][j] += a[i].x * bb[j].x + a[i].y * bb[j].y +
                             a[i].z * bb[j].z + a[i].w * bb[j].w;
    }

#pragma unroll
    for (int i = 0; i < 4; ++i) {
        int gr = rowbase + rg + 16 * i;
        if (gr < n) {
#pragma unroll
            for (int j = 0; j < 4; ++j)
                y[(size_t)gr * N_CLASSES + cg + 16 * j] = acc[i][j];
        }
    }
}

// ---------------------------------------------------------------------------
// One gather hop on 64-feature data: yout[c] = dinv[c]*( dinv[c]*yin[c]
//   + sum_{r in N_in(c)} dinv[r]*yin[r] )  [+ bias on the final hop]
// One wave per node, lane = feature.  Coalesced 256B gathers, one write.
// ---------------------------------------------------------------------------
__global__ __launch_bounds__(256) void hop_gather_kernel(const int* __restrict__ rowptr,
                                                         const int* __restrict__ adj,
                                                         const float* __restrict__ dinv,
                                                         const float* __restrict__ yin,
                                                         float* __restrict__ yout,
                                                         const float* __restrict__ bias,
                                                         int n) {
    int sub  = threadIdx.x >> 6;
    int lane = threadIdx.x & 63;
    int node = blockIdx.x * 4 + sub;
    if (node >= n) return;

    float dc = dinv[node];
    int s  = rowptr[node];
    int e2 = rowptr[node + 1];

    float acc = dc * yin[(size_t)node * N_CLASSES + lane];  // self loop
    int k = s;
    for (; k + 3 < e2; k += 4) {
        int r0 = adj[k], r1 = adj[k + 1], r2 = adj[k + 2], r3 = adj[k + 3];
        float d0 = dinv[r0], d1 = dinv[r1], d2 = dinv[r2], d3 = dinv[r3];
        float v0 = yin[(size_t)r0 * N_CLASSES + lane];
        float v1 = yin[(size_t)r1 * N_CLASSES + lane];
        float v2 = yin[(size_t)r2 * N_CLASSES + lane];
        float v3 = yin[(size_t)r3 * N_CLASSES + lane];
        acc += d0 * v0 + d1 * v1 + d2 * v2 + d3 * v3;
    }
    for (; k < e2; ++k) {
        int r = adj[k];
        acc += dinv[r] * yin[(size_t)r * N_CLASSES + lane];
    }
    acc *= dc;
    if (bias) acc += bias[lane];
    yout[(size_t)node * N_CLASSES + lane] = acc;
}

// ---------------------------------------------------------------------------
extern "C" void kernel_launch(void* const* d_in, const int* in_sizes, int n_in,
                              void* d_out, int out_size, void* d_ws, size_t ws_size,
                              hipStream_t stream) {
    const float* x     = (const float*)d_in[0];
    const int*   edges = (const int*)d_in[1];   // int64 ref -> int32 device, [2, E] flat
    const float* W     = (const float*)d_in[2]; // [64, 128]
    const float* b     = (const float*)d_in[3]; // [64]
    float*       out   = (float*)d_out;         // [N, 64]

    const int* row = edges;            // sources
    const int* col = edges + N_EDGES;  // targets

    char* ws = (char*)d_ws;
    int*   cnt    = (int*)(ws + 0);
    int*   rowptr = (int*)(ws + 256 * 1024);
    int*   cursor = (int*)(ws + 512 * 1024);
    float* dinv   = (float*)(ws + 768 * 1024);
    int*   bsum   = (int*)(ws + 960 * 1024);           // 196 ints
    int*   adj    = (int*)(ws + 1024 * 1024);          // 3.2 MB
    float* y      = (float*)(ws + 8 * 1024 * 1024);    // 12.8 MB
    float* z1     = (float*)(ws + 24 * 1024 * 1024);   // 12.8 MB

    const int nblk = (N_NODES + 255) / 256;  // 196

    // CSR build
    hipMemsetAsync(cnt, 0, N_NODES * sizeof(int), stream);
    count_kernel<<<(N_EDGES + 255) / 256, 256, 0, stream>>>(col, cnt, N_EDGES);
    block_sum_kernel<<<nblk, 256, 0, stream>>>(cnt, bsum, N_NODES);
    scan_bsum_kernel<<<1, 256, 0, stream>>>(bsum, nblk);
    apply_scan_kernel<<<nblk, 256, 0, stream>>>(cnt, bsum, rowptr, cursor, dinv, N_NODES);
    fill_kernel<<<(N_EDGES + 255) / 256, 256, 0, stream>>>(row, col, cursor, adj, N_EDGES);

    // y = x @ W^T   (S^2 x) W^T == S^2 (x W^T)
    gemm_kernel<<<(N_NODES + 63) / 64, 256, 0, stream>>>(x, W, y, N_NODES);

    // Two propagation hops; bias fused into the last one.
    hop_gather_kernel<<<(N_NODES + 3) / 4, 256, 0, stream>>>(rowptr, adj, dinv, y, z1, nullptr, N_NODES);
    hop_gather_kernel<<<(N_NODES + 3) / 4, 256, 0, stream>>>(rowptr, adj, dinv, z1, out, b, N_NODES);
}

// Round 6
// 195.584 us; speedup vs baseline: 15.7042x; 1.0002x over previous
//
#include <hip/hip_runtime.h>

#define N_NODES   50000
#define N_EDGES   800000
#define IN_FEAT   128
#define N_CLASSES 64
#define LDS_PAD   132   // 128 + 4 floats: row-to-row bank stride = 4, float4-aligned

// ---------------------------------------------------------------------------
// CSR build: histogram of targets (col), two-level scan, fill adjacency.
// ---------------------------------------------------------------------------
__global__ void count_kernel(const int* __restrict__ col, int* __restrict__ cnt, int e) {
    int i = blockIdx.x * blockDim.x + threadIdx.x;
    if (i < e) atomicAdd(&cnt[col[i]], 1);
}

__global__ __launch_bounds__(256) void block_sum_kernel(const int* __restrict__ cnt,
                                                        int* __restrict__ bsum, int n) {
    __shared__ int s[256];
    int t = threadIdx.x;
    int i = blockIdx.x * 256 + t;
    s[t] = (i < n) ? cnt[i] : 0;
    __syncthreads();
    for (int off = 128; off > 0; off >>= 1) {
        if (t < off) s[t] += s[t + off];
        __syncthreads();
    }
    if (t == 0) bsum[blockIdx.x] = s[0];
}

__global__ __launch_bounds__(256) void scan_bsum_kernel(int* __restrict__ bsum, int nb) {
    __shared__ int s[256];
    int t = threadIdx.x;
    s[t] = (t < nb) ? bsum[t] : 0;
    __syncthreads();
    for (int off = 1; off < 256; off <<= 1) {
        int add = (t >= off) ? s[t - off] : 0;
        __syncthreads();
        s[t] += add;
        __syncthreads();
    }
    if (t < nb) bsum[t] = s[t];  // inclusive sums
}

__global__ __launch_bounds__(256) void apply_scan_kernel(const int* __restrict__ cnt,
                                                         const int* __restrict__ bsum,
                                                         int* __restrict__ rowptr,
                                                         int* __restrict__ cursor,
                                                         float* __restrict__ dinv, int n) {
    __shared__ int s[256];
    int b = blockIdx.x, t = threadIdx.x;
    int i = b * 256 + t;
    int v = (i < n) ? cnt[i] : 0;
    s[t] = v;
    __syncthreads();
    for (int off = 1; off < 256; off <<= 1) {
        int add = (t >= off) ? s[t - off] : 0;
        __syncthreads();
        s[t] += add;
        __syncthreads();
    }
    int boff = (b > 0) ? bsum[b - 1] : 0;
    if (i < n) {
        int excl = boff + s[t] - v;
        rowptr[i] = excl;
        cursor[i] = excl;
        dinv[i]   = rsqrtf((float)(v + 1));  // +1 self loop
    }
    if (i == n - 1) rowptr[n] = boff + s[t];
}

__global__ void fill_kernel(const int* __restrict__ row, const int* __restrict__ col,
                            int* __restrict__ cursor, int* __restrict__ adj, int e) {
    int i = blockIdx.x * blockDim.x + threadIdx.x;
    if (i < e) {
        int c = col[i];
        int pos = atomicAdd(&cursor[c], 1);
        adj[pos] = row[i];
    }
}

// ---------------------------------------------------------------------------
// Tiled u = dinv .* (x @ W^T).  64x64 tile per 256-thread block; x-tile and W
// in LDS (pad 132 -> conflict-free b128); 4x4 register tile per thread at
// strided rows/cols {g+16i}.  u = D^{-1/2} (x W^T): with scaling hoisted here,
// both hops become pure unweighted neighbor sums.
// ---------------------------------------------------------------------------
__global__ __launch_bounds__(256) void gemm_kernel(const float* __restrict__ x,
                                                   const float* __restrict__ W,
                                                   const float* __restrict__ dinv,
                                                   float* __restrict__ u, int n) {
    __shared__ float xs[64][LDS_PAD];
    __shared__ float ws[64][LDS_PAD];
    int t = threadIdx.x;
    int rowbase = blockIdx.x * 64;

    for (int i = t; i < 64 * 32; i += 256) {
        int r  = i >> 5;
        int kk = i & 31;
        *(float4*)(&ws[r][kk * 4]) = *(const float4*)(W + (size_t)r * IN_FEAT + kk * 4);
        int gr = rowbase + r;
        float4 v = make_float4(0.f, 0.f, 0.f, 0.f);
        if (gr < n) v = *(const float4*)(x + (size_t)gr * IN_FEAT + kk * 4);
        *(float4*)(&xs[r][kk * 4]) = v;
    }
    __syncthreads();

    int rg = t >> 4;   // rows rg, rg+16, rg+32, rg+48
    int cg = t & 15;   // cols cg, cg+16, cg+32, cg+48
    float acc[4][4] = {};

    for (int kk = 0; kk < 32; ++kk) {
        float4 a[4], bb[4];
#pragma unroll
        for (int i = 0; i < 4; ++i) a[i]  = *(float4*)(&xs[rg + 16 * i][kk * 4]);
#pragma unroll
        for (int j = 0; j < 4; ++j) bb[j] = *(float4*)(&ws[cg + 16 * j][kk * 4]);
#pragma unroll
        for (int i = 0; i < 4; ++i)
#pragma unroll
            for (int j = 0; j < 4; ++j)
                acc[i][j] += a[i].x * bb[j].x + a[i].y * bb[j].y +
                             a[i].z * bb[j].z + a[i].w * bb[j].w;
    }

#pragma unroll
    for (int i = 0; i < 4; ++i) {
        int gr = rowbase + rg + 16 * i;
        if (gr < n) {
            float d = dinv[gr];
#pragma unroll
            for (int j = 0; j < 4; ++j)
                u[(size_t)gr * N_CLASSES + cg + 16 * j] = d * acc[i][j];
        }
    }
}

// ---------------------------------------------------------------------------
// Pure-sum hop: t[c] = yin[c] + sum_{r in N_in(c)} yin[r], then
// yout[c] = scale(c)*t[c] (+ bias).  mode 0: scale = dinv^2 (middle hop).
// mode 1: scale = dinv, + bias (final hop).  Inner loop: broadcast index
// load + coalesced 256B row load + add (no per-edge dinv traffic).
// ---------------------------------------------------------------------------
__global__ __launch_bounds__(256) void hop_sum_kernel(const int* __restrict__ rowptr,
                                                      const int* __restrict__ adj,
                                                      const float* __restrict__ dinv,
                                                      const float* __restrict__ yin,
                                                      float* __restrict__ yout,
                                                      const float* __restrict__ bias,
                                                      int mode, int n) {
    int sub  = threadIdx.x >> 6;
    int lane = threadIdx.x & 63;
    int node = blockIdx.x * 4 + sub;
    if (node >= n) return;

    int s  = rowptr[node];
    int e2 = rowptr[node + 1];

    float acc = yin[(size_t)node * N_CLASSES + lane];  // self loop
    int k = s;
    for (; k + 3 < e2; k += 4) {
        float v0 = yin[(size_t)adj[k + 0] * N_CLASSES + lane];
        float v1 = yin[(size_t)adj[k + 1] * N_CLASSES + lane];
        float v2 = yin[(size_t)adj[k + 2] * N_CLASSES + lane];
        float v3 = yin[(size_t)adj[k + 3] * N_CLASSES + lane];
        acc += (v0 + v1) + (v2 + v3);
    }
    for (; k < e2; ++k)
        acc += yin[(size_t)adj[k] * N_CLASSES + lane];

    float d = dinv[node];
    if (mode == 0) {
        yout[(size_t)node * N_CLASSES + lane] = d * d * acc;
    } else {
        yout[(size_t)node * N_CLASSES + lane] = d * acc + bias[lane];
    }
}

// ---------------------------------------------------------------------------
extern "C" void kernel_launch(void* const* d_in, const int* in_sizes, int n_in,
                              void* d_out, int out_size, void* d_ws, size_t ws_size,
                              hipStream_t stream) {
    const float* x     = (const float*)d_in[0];
    const int*   edges = (const int*)d_in[1];   // int64 ref -> int32 device, [2, E] flat
    const float* W     = (const float*)d_in[2]; // [64, 128]
    const float* b     = (const float*)d_in[3]; // [64]
    float*       out   = (float*)d_out;         // [N, 64]

    const int* row = edges;            // sources
    const int* col = edges + N_EDGES;  // targets

    char* ws = (char*)d_ws;
    int*   cnt    = (int*)(ws + 0);
    int*   rowptr = (int*)(ws + 256 * 1024);
    int*   cursor = (int*)(ws + 512 * 1024);
    float* dinv   = (float*)(ws + 768 * 1024);
    int*   bsum   = (int*)(ws + 960 * 1024);           // 196 ints
    int*   adj    = (int*)(ws + 1024 * 1024);          // 3.2 MB
    float* u      = (float*)(ws + 8 * 1024 * 1024);    // 12.8 MB
    float* w1     = (float*)(ws + 24 * 1024 * 1024);   // 12.8 MB

    const int nblk = (N_NODES + 255) / 256;  // 196

    // CSR build + dinv
    hipMemsetAsync(cnt, 0, N_NODES * sizeof(int), stream);
    count_kernel<<<(N_EDGES + 255) / 256, 256, 0, stream>>>(col, cnt, N_EDGES);
    block_sum_kernel<<<nblk, 256, 0, stream>>>(cnt, bsum, N_NODES);
    scan_bsum_kernel<<<1, 256, 0, stream>>>(bsum, nblk);
    apply_scan_kernel<<<nblk, 256, 0, stream>>>(cnt, bsum, rowptr, cursor, dinv, N_NODES);
    fill_kernel<<<(N_EDGES + 255) / 256, 256, 0, stream>>>(row, col, cursor, adj, N_EDGES);

    // u = D^{-1/2} (x @ W^T)
    gemm_kernel<<<(N_NODES + 63) / 64, 256, 0, stream>>>(x, W, dinv, u, N_NODES);

    // hop1: w1 = D^{-1} (A+I) u ;  hop2: out = D^{-1/2} (A+I) w1 + b
    hop_sum_kernel<<<(N_NODES + 3) / 4, 256, 0, stream>>>(rowptr, adj, dinv, u, w1, nullptr, 0, N_NODES);
    hop_sum_kernel<<<(N_NODES + 3) / 4, 256, 0, stream>>>(rowptr, adj, dinv, w1, out, b, 1, N_NODES);
}